// Round 7
// baseline (233.007 us; speedup 1.0000x reference)
//
#include <hip/hip_runtime.h>
#include <hip/hip_bf16.h>

// Problem constants (T,S,W,D,C,K) = (16,16,10,512,64,512)
#define W_  10
#define D_  512
#define SW_ 160      // S*W
#define N1_ 1024     // 2*D
#define KT_ 512      // triplets per (t,w)

typedef __bf16 bf16x8 __attribute__((ext_vector_type(8)));
typedef float  f32x4  __attribute__((ext_vector_type(4)));

// async global->LDS, 16B per lane (global addr per-lane; LDS dest = wave base + lane*16)
__device__ __forceinline__ void async16(const void* g, void* l) {
  __builtin_amdgcn_global_load_lds(
      (__attribute__((address_space(1))) void*)(g),
      (__attribute__((address_space(3))) void*)(l), 16, 0, 0);
}

__device__ __forceinline__ float lo16(unsigned v) { return __uint_as_float(v << 16); }
__device__ __forceinline__ float hi16(unsigned v) { return __uint_as_float(v & 0xffff0000u); }
__device__ __forceinline__ unsigned short f2bu(float x) {
  __hip_bfloat16 b = __float2bfloat16(x);
  return *(unsigned short*)&b;
}
__device__ __forceinline__ float bu2f(unsigned short u) {
  return __uint_as_float(((unsigned)u) << 16);
}

// ================= K0: prep — cast x, transpose W1, hi/lo tail weights, bc2
// grid: [0,256) cast | [256,1792) W1 | [1792,3360) W2/W3/W4/Wc | 3360 bc2
__global__ __launch_bounds__(256) void prep(
    const float* __restrict__ xin, const float* __restrict__ W1,
    const float* __restrict__ W2, const float* __restrict__ W3,
    const float* __restrict__ W4, const float* __restrict__ Wc,
    const float* __restrict__ b4, const float* __restrict__ bc,
    unsigned short* __restrict__ xbf, unsigned short* __restrict__ w1t,
    unsigned short* __restrict__ W2h, unsigned short* __restrict__ W2l,
    unsigned short* __restrict__ W3h, unsigned short* __restrict__ W3l,
    unsigned short* __restrict__ W4nh, unsigned short* __restrict__ W4nl,
    unsigned short* __restrict__ Wch, unsigned short* __restrict__ Wcl,
    float* __restrict__ bc2)
{
  __shared__ float tile[32 * 33];
  const int bx = blockIdx.x, tid = threadIdx.x;

  if (bx < 256) {  // cast 1310720 floats -> bf16
    int base = bx * 256 + tid;
#pragma unroll
    for (int rep = 0; rep < 5; ++rep) {
      int e = (rep * 65536 + base) * 4;
      float4 v = *(const float4*)(xin + e);
      ushort4 o = { f2bu(v.x), f2bu(v.y), f2bu(v.z), f2bu(v.w) };
      *(ushort4*)(xbf + e) = o;
    }
    return;
  }

  if (bx == 3360) {  // bc2[n] = sum_m b4[m]*Wc[m][n] + bc[n]
    int n = tid & 63, part = tid >> 6;
    float acc = 0.f;
    for (int m = part * 128; m < part * 128 + 128; ++m)
      acc += b4[m] * Wc[m * 64 + n];
    tile[tid] = acc;
    __syncthreads();
    if (tid < 64)
      bc2[n] = tile[n] + tile[64 + n] + tile[128 + n] + tile[192 + n] + bc[n];
    return;
  }

  const int c = tid & 31, rr = tid >> 5;
  if (bx < 1792) {  // W1 [1536][1024] f32 -> w1t [1024][1536] bf16
    int q = bx - 256;
    int n0 = (q & 31) << 5, k0 = (q >> 5) << 5;
#pragma unroll
    for (int i = 0; i < 4; ++i) {
      int r = rr + i * 8;
      tile[r * 33 + c] = W1[(size_t)(k0 + r) * N1_ + n0 + c];
    }
    __syncthreads();
#pragma unroll
    for (int i = 0; i < 4; ++i) {
      int r = rr + i * 8;
      w1t[(size_t)(n0 + r) * 1536 + k0 + c] = f2bu(tile[c * 33 + r]);
    }
    return;
  }

  int q = bx - 1792;
  if (q >= 1024 && q < 1536) {  // W4 -> normal-orientation hi/lo [1024][512]
    int rt = (q - 1024) >> 4, ct = (q - 1024) & 15;
    int r0 = rt << 5, c0 = ct << 5;
#pragma unroll
    for (int i = 0; i < 4; ++i) {
      int r = rr + i * 8;
      size_t off = (size_t)(r0 + r) * 512 + c0 + c;
      float v = W4[off];
      unsigned short h = f2bu(v);
      W4nh[off] = h; W4nl[off] = f2bu(v - bu2f(h));
    }
    return;
  }

  // W2/W3/Wc: [R][C] f32 -> [C][R] bf16 hi + lo
  const float* src; unsigned short *dh, *dl; int R, C, rt, ct;
  if (q < 512)       { src = W2; dh = W2h; dl = W2l; R = 1024; C = 512;  rt = q >> 4;          ct = q & 15; }
  else if (q < 1024) { src = W3; dh = W3h; dl = W3l; R = 512;  C = 1024; rt = (q - 512) >> 5;  ct = (q - 512) & 31; }
  else               { src = Wc; dh = Wch; dl = Wcl; R = 512;  C = 64;   rt = (q - 1536) >> 1; ct = (q - 1536) & 1; }
  int r0 = rt << 5, c0 = ct << 5;
#pragma unroll
  for (int i = 0; i < 4; ++i) {
    int r = rr + i * 8;
    tile[r * 33 + c] = src[(size_t)(r0 + r) * C + c0 + c];
  }
  __syncthreads();
#pragma unroll
  for (int i = 0; i < 4; ++i) {
    int r = rr + i * 8;
    float v = tile[c * 33 + r];
    unsigned short h = f2bu(v);
    size_t off = (size_t)(c0 + r) * R + r0 + c;
    dh[off] = h;
    dl[off] = f2bu(v - bu2f(h));
  }
}

// ================= K1: fused P-tile GEMM + gather/relu/reduce -> Hs (bf16 hi/lo)
__global__ __launch_bounds__(256) void group_kernel(
    const unsigned short* __restrict__ xbf,   // [16][160][512]
    const unsigned short* __restrict__ w1t,   // [1024][1536]
    const int* __restrict__ tidx,             // [16][10][3][512]
    const float* __restrict__ b1,             // [1024]
    unsigned short* __restrict__ Hsh,         // [160][1024]
    unsigned short* __restrict__ Hsl)
{
  __shared__ __align__(16) char smem[34560];
  char* Abuf  = smem;                       // [0,20480) phase 1
  char* Bbuf  = smem + 20480;               // [20480,32768) phase 1
  char* Ptile = smem;                       // [0,34560) phase 2 (overlaps staging)

  const int tid = threadIdx.x;
  const int bx  = blockIdx.x;
  const int t   = bx >> 5;
  const int n0  = (bx & 31) << 5;           // 32-col output window

  const int ln = tid & 63, wv = tid >> 6;
  const int wr = wv >> 1, wc = wv & 1;      // 2x2 wave grid: 80 rows x 48 cols each
  const int col16 = ln & 15, quad = ln >> 4;

  const unsigned short* xt = xbf + (size_t)t * (SW_ * D_);

  int aoff[5], lofA[5];
#pragma unroll
  for (int s = 0; s < 5; ++s) {             // A: 160 rows x 8 chunks = 1280
    int i = s * 256 + tid, r = i >> 3, q = i & 7;
    aoff[s] = r * 512 + ((q ^ (r & 7)) << 3);
    lofA[s] = i << 4;
  }
  int boff[3], lofB[3];
#pragma unroll
  for (int s = 0; s < 3; ++s) {             // B: 96 rows x 8 chunks = 768
    int i = s * 256 + tid, r = i >> 3, q = i & 7;
    int nc = r & 31, j = r >> 5;
    boff[s] = (n0 + nc) * 1536 + j * 512 + ((q ^ (r & 7)) << 3);
    lofB[s] = i << 4;
  }

  f32x4 acc[5][3];
#pragma unroll
  for (int a = 0; a < 5; ++a)
#pragma unroll
    for (int b = 0; b < 3; ++b)
      acc[a][b] = (f32x4){0.f, 0.f, 0.f, 0.f};

  // ---- phase 1: K-loop
#pragma unroll 1
  for (int kk = 0; kk < 512; kk += 64) {
    __syncthreads();
#pragma unroll
    for (int s = 0; s < 5; ++s) async16(xt + aoff[s] + kk, Abuf + lofA[s]);
#pragma unroll
    for (int s = 0; s < 3; ++s) async16(w1t + boff[s] + kk, Bbuf + lofB[s]);
    __syncthreads();

#pragma unroll
    for (int ks = 0; ks < 2; ++ks) {
      const int qq = (ks << 2) + quad;
      bf16x8 af[5], bfr[3];
#pragma unroll
      for (int a = 0; a < 5; ++a) {
        int rm = wr * 80 + a * 16 + col16;
        af[a] = *(const bf16x8*)(Abuf + rm * 128 + ((qq ^ (rm & 7)) << 4));
      }
#pragma unroll
      for (int b = 0; b < 3; ++b) {
        int rn = wc * 48 + b * 16 + col16;
        bfr[b] = *(const bf16x8*)(Bbuf + rn * 128 + ((qq ^ (rn & 7)) << 4));
      }
#pragma unroll
      for (int a = 0; a < 5; ++a)
#pragma unroll
        for (int b = 0; b < 3; ++b)
          acc[a][b] = __builtin_amdgcn_mfma_f32_16x16x32_bf16(af[a], bfr[b], acc[a][b], 0, 0, 0);
    }
  }

  __syncthreads();   // staging reads done; smem becomes Ptile

  // ---- write P to LDS as bf16, layout [j][sw][nc], row stride 72 B
#pragma unroll
  for (int a = 0; a < 5; ++a)
#pragma unroll
    for (int b = 0; b < 3; ++b) {
      int cidx = wc * 48 + b * 16 + col16;     // 0..95
      int j = cidx >> 5, nc = cidx & 31;
      int mb = wr * 80 + a * 16 + quad * 4;
#pragma unroll
      for (int r = 0; r < 4; ++r)
        *(unsigned short*)(Ptile + (j * 160 + mb + r) * 72 + nc * 2) =
            f2bu(acc[a][b][r]);
    }
  __syncthreads();   // Ptile visible to all waves; no more barriers below

  // ---- phase 2: each wave owns w in {wv, wv+4, wv+8}; idx from global w/ lookahead
  const int nq = ln & 7;                    // 4 cols: n0 + nq*4 ..+3
  const int kq = ln >> 3;                   // 0..7
  const float4 bias4 = *(const float4*)(b1 + n0 + (nq << 2));

  for (int w = wv; w < 10; w += 4) {
    const int* ip = tidx + (size_t)(t * 10 + w) * 1536 + (kq << 2);
    f32x4 a4 = (f32x4){0.f, 0.f, 0.f, 0.f};
    int4 c0 = *(const int4*)(ip);
    int4 c1 = *(const int4*)(ip + 512);
    int4 c2 = *(const int4*)(ip + 1024);
#pragma unroll 4
    for (int u = 0; u < 16; ++u) {
      int4 nx0 = c0, nx1 = c1, nx2 = c2;
      if (u < 15) {
        const int* p2 = ip + (u + 1) * 32;
        nx0 = *(const int4*)(p2);
        nx1 = *(const int4*)(p2 + 512);
        nx2 = *(const int4*)(p2 + 1024);
      }
#define STEP(IA, IB, IC)                                                          \
      {                                                                           \
        uint2 p0 = *(const uint2*)(Ptile + (IA) * 72 + (nq << 3));                \
        uint2 p1 = *(const uint2*)(Ptile + 11520 + (IB) * 72 + (nq << 3));        \
        uint2 p2v = *(const uint2*)(Ptile + 23040 + (IC) * 72 + (nq << 3));       \
        a4.x += fmaxf(lo16(p0.x) + lo16(p1.x) + lo16(p2v.x) + bias4.x, 0.f);      \
        a4.y += fmaxf(hi16(p0.x) + hi16(p1.x) + hi16(p2v.x) + bias4.y, 0.f);      \
        a4.z += fmaxf(lo16(p0.y) + lo16(p1.y) + lo16(p2v.y) + bias4.z, 0.f);      \
        a4.w += fmaxf(hi16(p0.y) + hi16(p1.y) + hi16(p2v.y) + bias4.w, 0.f);      \
      }
      STEP(c0.x, c1.x, c2.x)
      STEP(c0.y, c1.y, c2.y)
      STEP(c0.z, c1.z, c2.z)
      STEP(c0.w, c1.w, c2.w)
#undef STEP
      c0 = nx0; c1 = nx1; c2 = nx2;
    }
    // reduce over kq (lane bits 3..5) — wave-local
#pragma unroll
    for (int off = 8; off <= 32; off <<= 1) {
      a4.x += __shfl_xor(a4.x, off);
      a4.y += __shfl_xor(a4.y, off);
      a4.z += __shfl_xor(a4.z, off);
      a4.w += __shfl_xor(a4.w, off);
    }
    if (kq == 0) {
      size_t off = (size_t)(t * 10 + w) * N1_ + n0 + (nq << 2);
#pragma unroll
      for (int cc = 0; cc < 4; ++cc) {
        float s = a4[cc];
        unsigned short h = f2bu(s);
        Hsh[off + cc] = h; Hsl[off + cc] = f2bu(s - bu2f(h));
      }
    }
  }
}

// ---------------- templated tile GEMM: NA*16 rows x 64 cols, hi/lo bf16, BK=64
template <int NA>
__device__ __forceinline__ void gemm_t(
    char* sm,
    const unsigned short* __restrict__ Ah, const unsigned short* __restrict__ Al, int m0,
    const unsigned short* __restrict__ Bh, const unsigned short* __restrict__ Bl, int n0,
    int K, f32x4* acc, int tid)
{
  char* AH = sm;
  char* AL = sm + NA * 2048;
  char* BH = sm + NA * 4096;
  char* BL = BH + 8192;
  const int ACH = NA * 128;   // 16-B chunks per A buffer
  const int ln = tid & 63, wv = tid >> 6, col16 = ln & 15, quad = ln >> 4;
#pragma unroll 1
  for (int kk = 0; kk < K; kk += 64) {
    __syncthreads();
    for (int i = tid; i < 2 * ACH + 1024; i += 256) {
      if (i < ACH) {
        int r = i >> 3, q = i & 7;
        async16(Ah + (size_t)(m0 + r) * K + kk + ((q ^ (r & 7)) << 3), AH + (i << 4));
      } else if (i < 2 * ACH) {
        int j = i - ACH, r = j >> 3, q = j & 7;
        async16(Al + (size_t)(m0 + r) * K + kk + ((q ^ (r & 7)) << 3), AL + (j << 4));
      } else if (i < 2 * ACH + 512) {
        int j = i - 2 * ACH, r = j >> 3, q = j & 7;
        async16(Bh + (size_t)(n0 + r) * K + kk + ((q ^ (r & 7)) << 3), BH + (j << 4));
      } else {
        int j = i - 2 * ACH - 512, r = j >> 3, q = j & 7;
        async16(Bl + (size_t)(n0 + r) * K + kk + ((q ^ (r & 7)) << 3), BL + (j << 4));
      }
    }
    __syncthreads();
#pragma unroll
    for (int ks = 0; ks < 2; ++ks) {
      const int qq = (ks << 2) + quad;
      const int rn = (wv << 4) + col16;
      bf16x8 bh = *(const bf16x8*)(BH + rn * 128 + ((qq ^ (rn & 7)) << 4));
      bf16x8 bl = *(const bf16x8*)(BL + rn * 128 + ((qq ^ (rn & 7)) << 4));
#pragma unroll
      for (int a = 0; a < NA; ++a) {
        int rm = (a << 4) + col16;
        bf16x8 ah = *(const bf16x8*)(AH + rm * 128 + ((qq ^ (rm & 7)) << 4));
        bf16x8 al = *(const bf16x8*)(AL + rm * 128 + ((qq ^ (rm & 7)) << 4));
        acc[a] = __builtin_amdgcn_mfma_f32_16x16x32_bf16(ah, bh, acc[a], 0, 0, 0);
        acc[a] = __builtin_amdgcn_mfma_f32_16x16x32_bf16(ah, bl, acc[a], 0, 0, 0);
        acc[a] = __builtin_amdgcn_mfma_f32_16x16x32_bf16(al, bh, acc[a], 0, 0, 0);
      }
    }
  }
}

// ================= K2: stage-1 (g = Hs@W2 + 512*b2) + W4c = W4@Wc, one launch
__global__ __launch_bounds__(256) void t1_kernel(
    const unsigned short* __restrict__ Hsh, const unsigned short* __restrict__ Hsl,
    const unsigned short* __restrict__ W2h, const unsigned short* __restrict__ W2l,
    const float* __restrict__ b2,
    const unsigned short* __restrict__ W4nh, const unsigned short* __restrict__ W4nl,
    const unsigned short* __restrict__ Wch, const unsigned short* __restrict__ Wcl,
    unsigned short* __restrict__ gh, unsigned short* __restrict__ gl,
    unsigned short* __restrict__ W4ch, unsigned short* __restrict__ W4cl)
{
  __shared__ __align__(16) char sm[36864];
  const int bx = blockIdx.x, tid = threadIdx.x;
  const int ln = tid & 63, wv = tid >> 6, col16 = ln & 15, quad = ln >> 4;

  if (bx < 16) {  // g: [160][512], tiles 80x64
    f32x4 acc[5];
#pragma unroll
    for (int a = 0; a < 5; ++a) acc[a] = (f32x4){0.f, 0.f, 0.f, 0.f};
    int m0 = (bx & 1) * 80, n0 = (bx >> 1) << 6;
    gemm_t<5>(sm, Hsh, Hsl, m0, W2h, W2l, n0, 1024, acc, tid);
    const int col = n0 + (wv << 4) + col16;
    const float bb = b2[col] * (float)KT_;
#pragma unroll
    for (int a = 0; a < 5; ++a)
#pragma unroll
      for (int r = 0; r < 4; ++r) {
        int row = m0 + (a << 4) + (quad << 2) + r;
        float v = acc[a][r] + bb;
        unsigned short h = f2bu(v);
        size_t off = (size_t)row * 512 + col;
        gh[off] = h; gl[off] = f2bu(v - bu2f(h));
      }
  } else {        // W4c: [1024][64] = W4@Wc, tiles 64x64, stored transposed [64][1024]
    f32x4 acc[4];
#pragma unroll
    for (int a = 0; a < 4; ++a) acc[a] = (f32x4){0.f, 0.f, 0.f, 0.f};
    int m0 = (bx - 16) << 6;
    gemm_t<4>(sm, W4nh, W4nl, m0, Wch, Wcl, 0, 512, acc, tid);
    const int col = (wv << 4) + col16;
#pragma unroll
    for (int a = 0; a < 4; ++a)
#pragma unroll
      for (int r = 0; r < 4; ++r) {
        int row = m0 + (a << 4) + (quad << 2) + r;
        float v = acc[a][r];
        unsigned short h = f2bu(v);
        size_t off = (size_t)col * 1024 + row;
        W4ch[off] = h; W4cl[off] = f2bu(v - bu2f(h));
      }
  }
}

// ================= K3: u = relu(g@W3 + b3), grid (16,2)
__global__ __launch_bounds__(256) void t2_kernel(
    const unsigned short* __restrict__ gh, const unsigned short* __restrict__ gl,
    const unsigned short* __restrict__ W3h, const unsigned short* __restrict__ W3l,
    const float* __restrict__ b3,
    unsigned short* __restrict__ uh, unsigned short* __restrict__ ul)
{
  __shared__ __align__(16) char sm[36864];
  const int tid = threadIdx.x;
  const int m0 = blockIdx.y * 80, n0 = blockIdx.x << 6;
  const int ln = tid & 63, wv = tid >> 6, col16 = ln & 15, quad = ln >> 4;
  f32x4 acc[5];
#pragma unroll
  for (int a = 0; a < 5; ++a) acc[a] = (f32x4){0.f, 0.f, 0.f, 0.f};
  gemm_t<5>(sm, gh, gl, m0, W3h, W3l, n0, 512, acc, tid);
  const int col = n0 + (wv << 4) + col16;
  const float bb = b3[col];
#pragma unroll
  for (int a = 0; a < 5; ++a)
#pragma unroll
    for (int r = 0; r < 4; ++r) {
      int row = m0 + (a << 4) + (quad << 2) + r;
      float v = fmaxf(acc[a][r] + bb, 0.f);
      unsigned short h = f2bu(v);
      size_t off = (size_t)row * 1024 + col;
      uh[off] = h; ul[off] = f2bu(v - bu2f(h));
    }
}

// ================= K4: score = u@W4c + bc2, softmax(64). Grid 2 (80 rows each).
__global__ __launch_bounds__(256) void t3_kernel(
    const unsigned short* __restrict__ uh, const unsigned short* __restrict__ ul,
    const unsigned short* __restrict__ W4ch, const unsigned short* __restrict__ W4cl,
    const float* __restrict__ bc2, float* __restrict__ out)
{
  __shared__ __align__(16) char sm[36864];
  const int tid = threadIdx.x;
  const int m0 = blockIdx.x * 80;
  const int ln = tid & 63, wv = tid >> 6, col16 = ln & 15, quad = ln >> 4;
  f32x4 acc[5];
#pragma unroll
  for (int a = 0; a < 5; ++a) acc[a] = (f32x4){0.f, 0.f, 0.f, 0.f};
  gemm_t<5>(sm, uh, ul, m0, W4ch, W4cl, 0, 1024, acc, tid);

  __syncthreads();   // done with LDS frags; reuse as score buffer
  float* sc = (float*)sm;            // [80][64]
  float* rs = (float*)(sm + 20480);  // [80]
  const int col = (wv << 4) + col16;
  const float bb = bc2[col];
#pragma unroll
  for (int a = 0; a < 5; ++a)
#pragma unroll
    for (int r = 0; r < 4; ++r)
      sc[((a << 4) + (quad << 2) + r) * 64 + col] = acc[a][r] + bb;
  __syncthreads();
  if (tid < 80) {
    float m = -1e30f;
    for (int c = 0; c < 64; ++c) m = fmaxf(m, sc[tid * 64 + c]);
    float s = 0.f;
    for (int c = 0; c < 64; ++c) {
      float e = expf(sc[tid * 64 + c] - m);
      sc[tid * 64 + c] = e;
      s += e;
    }
    rs[tid] = 1.f / s;
  }
  __syncthreads();
#pragma unroll
  for (int p = 0; p < 20; ++p) {
    int f = p * 256 + tid, r = f >> 6, c = f & 63;
    out[(size_t)(m0 + r) * 64 + c] = sc[f] * rs[r];
  }
}

extern "C" void kernel_launch(void* const* d_in, const int* in_sizes, int n_in,
                              void* d_out, int out_size, void* d_ws, size_t ws_size,
                              hipStream_t stream) {
  const float* x_in = (const float*)d_in[0];
  const int*   tidx = (const int*)d_in[1];
  const float* W1 = (const float*)d_in[2];
  const float* b1 = (const float*)d_in[3];
  const float* W2 = (const float*)d_in[4];
  const float* b2 = (const float*)d_in[5];
  const float* W3 = (const float*)d_in[6];
  const float* b3 = (const float*)d_in[7];
  const float* W4 = (const float*)d_in[8];
  const float* b4 = (const float*)d_in[9];
  const float* Wc = (const float*)d_in[10];
  const float* bc = (const float*)d_in[11];
  float* out = (float*)d_out;
  (void)in_sizes; (void)n_in; (void)out_size; (void)ws_size;

  char* ws = (char*)d_ws;
  unsigned short* xbf  = (unsigned short*)(ws + 0);          // 2,621,440
  unsigned short* w1t  = (unsigned short*)(ws + 2621440);    // 3,145,728
  unsigned short* W2h  = (unsigned short*)(ws + 5767168);    // 1,048,576 each
  unsigned short* W2l  = (unsigned short*)(ws + 6815744);
  unsigned short* W3h  = (unsigned short*)(ws + 7864320);
  unsigned short* W3l  = (unsigned short*)(ws + 8912896);
  unsigned short* W4nh = (unsigned short*)(ws + 9961472);
  unsigned short* W4nl = (unsigned short*)(ws + 11010048);
  unsigned short* Wch  = (unsigned short*)(ws + 12058624);   // 65,536 each
  unsigned short* Wcl  = (unsigned short*)(ws + 12124160);
  unsigned short* Hsh  = (unsigned short*)(ws + 12189696);   // 327,680 each
  unsigned short* Hsl  = (unsigned short*)(ws + 12517376);
  unsigned short* gh   = (unsigned short*)(ws + 12845056);   // 163,840 each
  unsigned short* gl   = (unsigned short*)(ws + 13008896);
  unsigned short* uh   = (unsigned short*)(ws + 13172736);   // 327,680 each
  unsigned short* ul   = (unsigned short*)(ws + 13500416);
  unsigned short* W4ch = (unsigned short*)(ws + 13828096);   // 131,072 each
  unsigned short* W4cl = (unsigned short*)(ws + 13959168);
  float*          bc2  = (float*)(ws + 14090240);            // 256 B

  prep<<<3361, 256, 0, stream>>>(x_in, W1, W2, W3, W4, Wc, b4, bc,
                                 xbf, w1t, W2h, W2l, W3h, W3l, W4nh, W4nl,
                                 Wch, Wcl, bc2);

  group_kernel<<<512, 256, 0, stream>>>(xbf, w1t, tidx, b1, Hsh, Hsl);

  // g = Hs@W2 + 512*b2  (16 blocks)  ||  W4c = W4@Wc  (16 blocks)
  t1_kernel<<<32, 256, 0, stream>>>(Hsh, Hsl, W2h, W2l, b2,
                                    W4nh, W4nl, Wch, Wcl, gh, gl, W4ch, W4cl);
  // u = relu(g@W3 + b3)
  t2_kernel<<<dim3(16, 2), 256, 0, stream>>>(gh, gl, W3h, W3l, b3, uh, ul);
  // out = softmax(u@W4c + bc2)
  t3_kernel<<<2, 256, 0, stream>>>(uh, ul, W4ch, W4cl, bc2, out);
}

// Round 9
// 231.027 us; speedup vs baseline: 1.0086x; 1.0086x over previous
//
#include <hip/hip_runtime.h>
#include <hip/hip_bf16.h>

// Problem constants (T,S,W,D,C,K) = (16,16,10,512,64,512)
#define W_  10
#define D_  512
#define SW_ 160      // S*W
#define N1_ 1024     // 2*D
#define KT_ 512      // triplets per (t,w)

typedef __bf16 bf16x8 __attribute__((ext_vector_type(8)));
typedef float  f32x4  __attribute__((ext_vector_type(4)));

// async global->LDS, 16B per lane (global addr per-lane; LDS dest = wave base + lane*16)
__device__ __forceinline__ void async16(const void* g, void* l) {
  __builtin_amdgcn_global_load_lds(
      (__attribute__((address_space(1))) void*)(g),
      (__attribute__((address_space(3))) void*)(l), 16, 0, 0);
}

__device__ __forceinline__ float lo16(unsigned v) { return __uint_as_float(v << 16); }
__device__ __forceinline__ float hi16(unsigned v) { return __uint_as_float(v & 0xffff0000u); }
__device__ __forceinline__ unsigned short f2bu(float x) {
  __hip_bfloat16 b = __float2bfloat16(x);
  return *(unsigned short*)&b;
}
__device__ __forceinline__ float bu2f(unsigned short u) {
  return __uint_as_float(((unsigned)u) << 16);
}

// ================= K0: prep — cast x, transpose W1, hi/lo tail weights, init accumulators
// grid: [0,256) cast | [256,1792) W1 | [1792,3360) W2/W3/W4/Wc |
//       [3360,3440) g32 init | [3440,3600) u32 init | 3600 s32+bc2 init
__global__ __launch_bounds__(256) void prep(
    const float* __restrict__ xin, const float* __restrict__ W1,
    const float* __restrict__ W2, const float* __restrict__ W3,
    const float* __restrict__ W4, const float* __restrict__ Wc,
    const float* __restrict__ b2, const float* __restrict__ b3,
    const float* __restrict__ b4, const float* __restrict__ bc,
    unsigned short* __restrict__ xbf, unsigned short* __restrict__ w1t,
    unsigned short* __restrict__ W2h, unsigned short* __restrict__ W2l,
    unsigned short* __restrict__ W3h, unsigned short* __restrict__ W3l,
    unsigned short* __restrict__ W4nh, unsigned short* __restrict__ W4nl,
    unsigned short* __restrict__ Wch, unsigned short* __restrict__ Wcl,
    float* __restrict__ g32, float* __restrict__ u32, float* __restrict__ s32)
{
  __shared__ float tile[32 * 33];
  const int bx = blockIdx.x, tid = threadIdx.x;

  if (bx < 256) {  // cast 1310720 floats -> bf16
    int base = bx * 256 + tid;
#pragma unroll
    for (int rep = 0; rep < 5; ++rep) {
      int e = (rep * 65536 + base) * 4;
      float4 v = *(const float4*)(xin + e);
      ushort4 o = { f2bu(v.x), f2bu(v.y), f2bu(v.z), f2bu(v.w) };
      *(ushort4*)(xbf + e) = o;
    }
    return;
  }

  if (bx >= 3360) {
    if (bx < 3440) {        // g32[160][512] = 512*b2[n] broadcast
      int e = (bx - 3360) * 1024 + tid * 4;     // 80 blocks x 1024 floats
      int c = e & 511;
      float4 v = { 512.f * b2[c], 512.f * b2[c + 1], 512.f * b2[c + 2], 512.f * b2[c + 3] };
      *(float4*)(g32 + e) = v;
    } else if (bx < 3600) { // u32[160][1024] = b3[n] broadcast (row per block)
      int row = bx - 3440;
      float4 v = *(const float4*)(b3 + tid * 4);
      *(float4*)(u32 + (size_t)row * 1024 + tid * 4) = v;
    } else {                // s32[160][64] = bc2[n] = b4@Wc + bc
      int n = tid & 63, part = tid >> 6;
      float acc = 0.f;
      for (int m = part * 128; m < part * 128 + 128; ++m)
        acc += b4[m] * Wc[m * 64 + n];
      tile[tid] = acc;
      __syncthreads();
      __shared__ float bcs[64];
      if (tid < 64) bcs[n] = tile[n] + tile[64 + n] + tile[128 + n] + tile[192 + n] + bc[n];
      __syncthreads();
      for (int i = tid; i < 10240; i += 256) s32[i] = bcs[i & 63];
    }
    return;
  }

  const int c = tid & 31, rr = tid >> 5;
  if (bx < 1792) {  // W1 [1536][1024] f32 -> w1t [1024][1536] bf16
    int q = bx - 256;
    int n0 = (q & 31) << 5, k0 = (q >> 5) << 5;
#pragma unroll
    for (int i = 0; i < 4; ++i) {
      int r = rr + i * 8;
      tile[r * 33 + c] = W1[(size_t)(k0 + r) * N1_ + n0 + c];
    }
    __syncthreads();
#pragma unroll
    for (int i = 0; i < 4; ++i) {
      int r = rr + i * 8;
      w1t[(size_t)(n0 + r) * 1536 + k0 + c] = f2bu(tile[c * 33 + r]);
    }
    return;
  }

  int q = bx - 1792;
  if (q >= 1024 && q < 1536) {  // W4 -> natural-orientation hi/lo [1024][512]
    int rt = (q - 1024) >> 4, ct = (q - 1024) & 15;
    int r0 = rt << 5, c0 = ct << 5;
#pragma unroll
    for (int i = 0; i < 4; ++i) {
      int r = rr + i * 8;
      size_t off = (size_t)(r0 + r) * 512 + c0 + c;
      float v = W4[off];
      unsigned short h = f2bu(v);
      W4nh[off] = h; W4nl[off] = f2bu(v - bu2f(h));
    }
    return;
  }

  // W2/W3/Wc: [R][C] f32 -> [C][R] bf16 hi + lo
  const float* src; unsigned short *dh, *dl; int R, C, rt, ct;
  if (q < 512)       { src = W2; dh = W2h; dl = W2l; R = 1024; C = 512;  rt = q >> 4;          ct = q & 15; }
  else if (q < 1024) { src = W3; dh = W3h; dl = W3l; R = 512;  C = 1024; rt = (q - 512) >> 5;  ct = (q - 512) & 31; }
  else               { src = Wc; dh = Wch; dl = Wcl; R = 512;  C = 64;   rt = (q - 1536) >> 1; ct = (q - 1536) & 1; }
  int r0 = rt << 5, c0 = ct << 5;
#pragma unroll
  for (int i = 0; i < 4; ++i) {
    int r = rr + i * 8;
    tile[r * 33 + c] = src[(size_t)(r0 + r) * C + c0 + c];
  }
  __syncthreads();
#pragma unroll
  for (int i = 0; i < 4; ++i) {
    int r = rr + i * 8;
    float v = tile[c * 33 + r];
    unsigned short h = f2bu(v);
    size_t off = (size_t)(c0 + r) * R + r0 + c;
    dh[off] = h;
    dl[off] = f2bu(v - bu2f(h));
  }
}

// ---------------- LDS tile GEMM (used only by W4c blocks): NA*16 x 64, hi/lo, BK=64
template <int NA>
__device__ __forceinline__ void gemm_t(
    char* sm,
    const unsigned short* __restrict__ Ah, const unsigned short* __restrict__ Al, int m0,
    const unsigned short* __restrict__ Bh, const unsigned short* __restrict__ Bl, int n0,
    int K, f32x4* acc, int tid)
{
  char* AH = sm;
  char* AL = sm + NA * 2048;
  char* BH = sm + NA * 4096;
  char* BL = BH + 8192;
  const int ACH = NA * 128;
  const int ln = tid & 63, wv = tid >> 6, col16 = ln & 15, quad = ln >> 4;
#pragma unroll 1
  for (int kk = 0; kk < K; kk += 64) {
    __syncthreads();
    for (int i = tid; i < 2 * ACH + 1024; i += 256) {
      if (i < ACH) {
        int r = i >> 3, q = i & 7;
        async16(Ah + (size_t)(m0 + r) * K + kk + ((q ^ (r & 7)) << 3), AH + (i << 4));
      } else if (i < 2 * ACH) {
        int j = i - ACH, r = j >> 3, q = j & 7;
        async16(Al + (size_t)(m0 + r) * K + kk + ((q ^ (r & 7)) << 3), AL + (j << 4));
      } else if (i < 2 * ACH + 512) {
        int j = i - 2 * ACH, r = j >> 3, q = j & 7;
        async16(Bh + (size_t)(n0 + r) * K + kk + ((q ^ (r & 7)) << 3), BH + (j << 4));
      } else {
        int j = i - 2 * ACH - 512, r = j >> 3, q = j & 7;
        async16(Bl + (size_t)(n0 + r) * K + kk + ((q ^ (r & 7)) << 3), BL + (j << 4));
      }
    }
    __syncthreads();
#pragma unroll
    for (int ks = 0; ks < 2; ++ks) {
      const int qq = (ks << 2) + quad;
      const int rn = (wv << 4) + col16;
      bf16x8 bh = *(const bf16x8*)(BH + rn * 128 + ((qq ^ (rn & 7)) << 4));
      bf16x8 bl = *(const bf16x8*)(BL + rn * 128 + ((qq ^ (rn & 7)) << 4));
#pragma unroll
      for (int a = 0; a < NA; ++a) {
        int rm = (a << 4) + col16;
        bf16x8 ah = *(const bf16x8*)(AH + rm * 128 + ((qq ^ (rm & 7)) << 4));
        bf16x8 al = *(const bf16x8*)(AL + rm * 128 + ((qq ^ (rm & 7)) << 4));
        acc[a] = __builtin_amdgcn_mfma_f32_16x16x32_bf16(ah, bh, acc[a], 0, 0, 0);
        acc[a] = __builtin_amdgcn_mfma_f32_16x16x32_bf16(ah, bl, acc[a], 0, 0, 0);
        acc[a] = __builtin_amdgcn_mfma_f32_16x16x32_bf16(al, bh, acc[a], 0, 0, 0);
      }
    }
  }
}

// ================= K1: fused P-tile GEMM + gather/relu/reduce -> Hs32 (fp32)
//                      blocks [512,528): W4c = (W4@Wc)^T [64][1024] hi/lo
__global__ __launch_bounds__(256) void group_kernel(
    const unsigned short* __restrict__ xbf,   // [16][160][512]
    const unsigned short* __restrict__ w1t,   // [1024][1536]
    const int* __restrict__ tidx,             // [16][10][3][512]
    const float* __restrict__ b1,             // [1024]
    float* __restrict__ Hs32,                 // [160][1024] fp32
    const unsigned short* __restrict__ Wch, const unsigned short* __restrict__ Wcl,
    const unsigned short* __restrict__ W4nh, const unsigned short* __restrict__ W4nl,
    unsigned short* __restrict__ W4ch, unsigned short* __restrict__ W4cl)
{
  __shared__ __align__(16) char smem[34560];
  const int tid = threadIdx.x;
  const int bx  = blockIdx.x;
  const int ln = tid & 63, wv = tid >> 6;
  const int col16 = ln & 15, quad = ln >> 4;

  if (bx >= 512) {   // ---- W4c blocks: C^T[n][k] = sum_j Wct[n][j] * W4[k][j]
    const int kt = bx - 512;
    f32x4 acc4[4];
#pragma unroll
    for (int a = 0; a < 4; ++a) acc4[a] = (f32x4){0.f, 0.f, 0.f, 0.f};
    gemm_t<4>(smem, Wch, Wcl, 0, W4nh, W4nl, kt << 6, 512, acc4, tid);
    const int kcol = (kt << 6) + (wv << 4) + col16;
#pragma unroll
    for (int a = 0; a < 4; ++a)
#pragma unroll
      for (int r = 0; r < 4; ++r) {
        int n = (a << 4) + (quad << 2) + r;
        float v = acc4[a][r];
        unsigned short h = f2bu(v);
        size_t off = (size_t)n * 1024 + kcol;
        W4ch[off] = h; W4cl[off] = f2bu(v - bu2f(h));
      }
    return;
  }

  char* Abuf  = smem;                       // [0,20480) phase 1
  char* Bbuf  = smem + 20480;               // [20480,32768) phase 1
  char* Ptile = smem;                       // [0,34560) phase 2 (overlaps staging)

  const int t   = bx >> 5;
  const int n0  = (bx & 31) << 5;           // 32-col output window
  const int wr = wv >> 1, wc = wv & 1;      // 2x2 wave grid: 80 rows x 48 cols each

  const unsigned short* xt = xbf + (size_t)t * (SW_ * D_);

  int aoff[5], lofA[5];
#pragma unroll
  for (int s = 0; s < 5; ++s) {             // A: 160 rows x 8 chunks = 1280
    int i = s * 256 + tid, r = i >> 3, q = i & 7;
    aoff[s] = r * 512 + ((q ^ (r & 7)) << 3);
    lofA[s] = i << 4;
  }
  int boff[3], lofB[3];
#pragma unroll
  for (int s = 0; s < 3; ++s) {             // B: 96 rows x 8 chunks = 768
    int i = s * 256 + tid, r = i >> 3, q = i & 7;
    int nc = r & 31, j = r >> 5;
    boff[s] = (n0 + nc) * 1536 + j * 512 + ((q ^ (r & 7)) << 3);
    lofB[s] = i << 4;
  }

  f32x4 acc[5][3];
#pragma unroll
  for (int a = 0; a < 5; ++a)
#pragma unroll
    for (int b = 0; b < 3; ++b)
      acc[a][b] = (f32x4){0.f, 0.f, 0.f, 0.f};

  // ---- phase 1: K-loop
#pragma unroll 1
  for (int kk = 0; kk < 512; kk += 64) {
    __syncthreads();
#pragma unroll
    for (int s = 0; s < 5; ++s) async16(xt + aoff[s] + kk, Abuf + lofA[s]);
#pragma unroll
    for (int s = 0; s < 3; ++s) async16(w1t + boff[s] + kk, Bbuf + lofB[s]);
    __syncthreads();

#pragma unroll
    for (int ks = 0; ks < 2; ++ks) {
      const int qq = (ks << 2) + quad;
      bf16x8 af[5], bfr[3];
#pragma unroll
      for (int a = 0; a < 5; ++a) {
        int rm = wr * 80 + a * 16 + col16;
        af[a] = *(const bf16x8*)(Abuf + rm * 128 + ((qq ^ (rm & 7)) << 4));
      }
#pragma unroll
      for (int b = 0; b < 3; ++b) {
        int rn = wc * 48 + b * 16 + col16;
        bfr[b] = *(const bf16x8*)(Bbuf + rn * 128 + ((qq ^ (rn & 7)) << 4));
      }
#pragma unroll
      for (int a = 0; a < 5; ++a)
#pragma unroll
        for (int b = 0; b < 3; ++b)
          acc[a][b] = __builtin_amdgcn_mfma_f32_16x16x32_bf16(af[a], bfr[b], acc[a][b], 0, 0, 0);
    }
  }

  __syncthreads();   // staging reads done; smem becomes Ptile

  // ---- write P to LDS as bf16, layout [j][sw][nc], row stride 72 B
#pragma unroll
  for (int a = 0; a < 5; ++a)
#pragma unroll
    for (int b = 0; b < 3; ++b) {
      int cidx = wc * 48 + b * 16 + col16;     // 0..95
      int j = cidx >> 5, nc = cidx & 31;
      int mb = wr * 80 + a * 16 + quad * 4;
#pragma unroll
      for (int r = 0; r < 4; ++r)
        *(unsigned short*)(Ptile + (j * 160 + mb + r) * 72 + nc * 2) =
            f2bu(acc[a][b][r]);
    }
  __syncthreads();   // Ptile visible to all waves; no more barriers below

  // ---- phase 2: each wave owns w in {wv, wv+4, wv+8}; idx from global w/ lookahead
  const int nq = ln & 7;                    // 4 cols: n0 + nq*4 ..+3
  const int kq = ln >> 3;                   // 0..7
  const float4 bias4 = *(const float4*)(b1 + n0 + (nq << 2));

  for (int w = wv; w < 10; w += 4) {
    const int* ip = tidx + (size_t)(t * 10 + w) * 1536 + (kq << 2);
    f32x4 a4 = (f32x4){0.f, 0.f, 0.f, 0.f};
    int4 c0 = *(const int4*)(ip);
    int4 c1 = *(const int4*)(ip + 512);
    int4 c2 = *(const int4*)(ip + 1024);
#pragma unroll 4
    for (int u = 0; u < 16; ++u) {
      int4 nx0 = c0, nx1 = c1, nx2 = c2;
      if (u < 15) {
        const int* p2 = ip + (u + 1) * 32;
        nx0 = *(const int4*)(p2);
        nx1 = *(const int4*)(p2 + 512);
        nx2 = *(const int4*)(p2 + 1024);
      }
#define STEP(IA, IB, IC)                                                          \
      {                                                                           \
        uint2 p0 = *(const uint2*)(Ptile + (IA) * 72 + (nq << 3));                \
        uint2 p1 = *(const uint2*)(Ptile + 11520 + (IB) * 72 + (nq << 3));        \
        uint2 p2v = *(const uint2*)(Ptile + 23040 + (IC) * 72 + (nq << 3));       \
        a4.x += fmaxf(lo16(p0.x) + lo16(p1.x) + lo16(p2v.x) + bias4.x, 0.f);      \
        a4.y += fmaxf(hi16(p0.x) + hi16(p1.x) + hi16(p2v.x) + bias4.y, 0.f);      \
        a4.z += fmaxf(lo16(p0.y) + lo16(p1.y) + lo16(p2v.y) + bias4.z, 0.f);      \
        a4.w += fmaxf(hi16(p0.y) + hi16(p1.y) + hi16(p2v.y) + bias4.w, 0.f);      \
      }
      STEP(c0.x, c1.x, c2.x)
      STEP(c0.y, c1.y, c2.y)
      STEP(c0.z, c1.z, c2.z)
      STEP(c0.w, c1.w, c2.w)
#undef STEP
      c0 = nx0; c1 = nx1; c2 = nx2;
    }
#pragma unroll
    for (int off = 8; off <= 32; off <<= 1) {
      a4.x += __shfl_xor(a4.x, off);
      a4.y += __shfl_xor(a4.y, off);
      a4.z += __shfl_xor(a4.z, off);
      a4.w += __shfl_xor(a4.w, off);
    }
    if (kq == 0)
      *(f32x4*)(Hs32 + (size_t)(t * 10 + w) * N1_ + n0 + (nq << 2)) = a4;
  }
}

// ================= K2: barrier-free K-split tail GEMM.
// out[m][n] += A_chunk @ B_chunk (atomicAdd fp32). A fp32 (optionally relu'd),
// converted to bf16 hi/lo in registers; B bf16 hi/lo; 3-MFMA compensated product.
// grid (n_tiles, m_tiles=2, k_chunks); block = 80 rows x 64 cols, waves split cols.
__global__ __launch_bounds__(256) void kgemm(
    const float* __restrict__ A, int lda,
    const unsigned short* __restrict__ Bh, const unsigned short* __restrict__ Bl,
    int Kb, int KC, int do_relu,
    float* __restrict__ out, int ldo)
{
  const int tid = threadIdx.x;
  const int m0 = blockIdx.y * 80, n0 = blockIdx.x << 6, kc0 = blockIdx.z * KC;
  const int ln = tid & 63, wv = tid >> 6, col16 = ln & 15, quad = ln >> 4;
  const int nrow = n0 + (wv << 4) + col16;

  const float* Ap[5];
#pragma unroll
  for (int a = 0; a < 5; ++a)
    Ap[a] = A + (size_t)(m0 + (a << 4) + col16) * lda + (quad << 3) + kc0;
  const unsigned short* Bhp = Bh + (size_t)nrow * Kb + (quad << 3) + kc0;
  const unsigned short* Blp = Bl + (size_t)nrow * Kb + (quad << 3) + kc0;

  f32x4 acc[5];
#pragma unroll
  for (int a = 0; a < 5; ++a) acc[a] = (f32x4){0.f, 0.f, 0.f, 0.f};

#pragma unroll 2
  for (int kk = 0; kk < 256; kk += 32) {   // KC fixed at 256
    bf16x8 bh = *(const bf16x8*)(Bhp + kk);
    bf16x8 bl = *(const bf16x8*)(Blp + kk);
#pragma unroll
    for (int a = 0; a < 5; ++a) {
      float4 x = *(const float4*)(Ap[a] + kk);
      float4 y = *(const float4*)(Ap[a] + kk + 4);
      float vv[8] = {x.x, x.y, x.z, x.w, y.x, y.y, y.z, y.w};
      union { unsigned short u[8]; bf16x8 v; } H, L;
#pragma unroll
      for (int j = 0; j < 8; ++j) {
        float f = do_relu ? fmaxf(vv[j], 0.f) : vv[j];
        unsigned short h = f2bu(f);
        H.u[j] = h;
        L.u[j] = f2bu(f - bu2f(h));
      }
      acc[a] = __builtin_amdgcn_mfma_f32_16x16x32_bf16(H.v, bh, acc[a], 0, 0, 0);
      acc[a] = __builtin_amdgcn_mfma_f32_16x16x32_bf16(H.v, bl, acc[a], 0, 0, 0);
      acc[a] = __builtin_amdgcn_mfma_f32_16x16x32_bf16(L.v, bh, acc[a], 0, 0, 0);
    }
  }

#pragma unroll
  for (int a = 0; a < 5; ++a)
#pragma unroll
    for (int r = 0; r < 4; ++r)
      atomicAdd(out + (size_t)(m0 + (a << 4) + (quad << 2) + r) * ldo + nrow, acc[a][r]);
}

// ================= K3: softmax over 64 cols. Grid 2 x 80 rows.
__global__ __launch_bounds__(256) void softmax_kernel(
    const float* __restrict__ s32, float* __restrict__ out)
{
  __shared__ float sc[80 * 64];
  __shared__ float rs[80];
  const int m0 = blockIdx.x * 80, tid = threadIdx.x;
  for (int i = tid; i < 5120; i += 256) sc[i] = s32[(size_t)m0 * 64 + i];
  __syncthreads();
  if (tid < 80) {
    float m = -1e30f;
    for (int c = 0; c < 64; ++c) m = fmaxf(m, sc[tid * 64 + c]);
    float s = 0.f;
    for (int c = 0; c < 64; ++c) {
      float e = expf(sc[tid * 64 + c] - m);
      sc[tid * 64 + c] = e;
      s += e;
    }
    rs[tid] = 1.f / s;
  }
  __syncthreads();
#pragma unroll
  for (int p = 0; p < 20; ++p) {
    int f = p * 256 + tid, r = f >> 6, c = f & 63;
    out[(size_t)(m0 + r) * 64 + c] = sc[f] * rs[r];
  }
}

extern "C" void kernel_launch(void* const* d_in, const int* in_sizes, int n_in,
                              void* d_out, int out_size, void* d_ws, size_t ws_size,
                              hipStream_t stream) {
  const float* x_in = (const float*)d_in[0];
  const int*   tidx = (const int*)d_in[1];
  const float* W1 = (const float*)d_in[2];
  const float* b1 = (const float*)d_in[3];
  const float* W2 = (const float*)d_in[4];
  const float* b2 = (const float*)d_in[5];
  const float* W3 = (const float*)d_in[6];
  const float* b3 = (const float*)d_in[7];
  const float* W4 = (const float*)d_in[8];
  const float* b4 = (const float*)d_in[9];
  const float* Wc = (const float*)d_in[10];
  const float* bc = (const float*)d_in[11];
  float* out = (float*)d_out;
  (void)in_sizes; (void)n_in; (void)out_size; (void)ws_size;

  char* ws = (char*)d_ws;
  unsigned short* xbf  = (unsigned short*)(ws + 0);          // 2,621,440
  unsigned short* w1t  = (unsigned short*)(ws + 2621440);    // 3,145,728
  unsigned short* W2h  = (unsigned short*)(ws + 5767168);    // 1,048,576 each
  unsigned short* W2l  = (unsigned short*)(ws + 6815744);
  unsigned short* W3h  = (unsigned short*)(ws + 7864320);
  unsigned short* W3l  = (unsigned short*)(ws + 8912896);
  unsigned short* W4nh = (unsigned short*)(ws + 9961472);
  unsigned short* W4nl = (unsigned short*)(ws + 11010048);
  unsigned short* Wch  = (unsigned short*)(ws + 12058624);   // 65,536 each
  unsigned short* Wcl  = (unsigned short*)(ws + 12124160);
  float*          Hs32 = (float*)(ws + 12189696);            // 655,360
  float*          g32  = (float*)(ws + 12845056);            // 327,680
  float*          u32  = (float*)(ws + 13172736);            // 655,360
  float*          s32  = (float*)(ws + 13828096);            // 40,960
  unsigned short* W4ch = (unsigned short*)(ws + 13869056);   // 131,072 each
  unsigned short* W4cl = (unsigned short*)(ws + 14000128);   // -> 14,131,200

  prep<<<3601, 256, 0, stream>>>(x_in, W1, W2, W3, W4, Wc, b2, b3, b4, bc,
                                 xbf, w1t, W2h, W2l, W3h, W3l, W4nh, W4nl,
                                 Wch, Wcl, g32, u32, s32);

  // group (512 blocks) + W4c = (W4@Wc)^T (16 blocks)
  group_kernel<<<528, 256, 0, stream>>>(xbf, w1t, tidx, b1, Hs32,
                                        Wch, Wcl, W4nh, W4nl, W4ch, W4cl);

  // g32 += Hs32 @ W2      (init 512*b2)
  kgemm<<<dim3(8, 2, 4), 256, 0, stream>>>(Hs32, 1024, W2h, W2l, 1024, 256, 0, g32, 512);
  // u32 += g32 @ W3       (init b3; relu deferred to consumer)
  kgemm<<<dim3(16, 2, 2), 256, 0, stream>>>(g32, 512, W3h, W3l, 512, 256, 0, u32, 1024);
  // s32 += relu(u32) @ W4c (init b4@Wc + bc)
  kgemm<<<dim3(1, 2, 4), 256, 0, stream>>>(u32, 1024, W4ch, W4cl, 1024, 256, 1, s32, 64);
  // out = softmax(s32)
  softmax_kernel<<<2, 256, 0, stream>>>(s32, out);
}